// Round 2
// baseline (174.504 us; speedup 1.0000x reference)
//
#include <hip/hip_runtime.h>
#include <math.h>

// EnhancedFinancialGAT — analytical collapse (see Round 0 proof: identical node
// rows + per-dst softmax summing to 1 via guaranteed self-loop => every GAT
// layer is a dense 256->256 relu layer; edges/attention numerically irrelevant).
//
// Round 2: coalesced weight access. Previous kernel had each lane read its own
// weight row => 64 scattered cache lines per vmem instruction => memory-pipe
// transaction-bound (~16K cycles/layer). Now 4 consecutive lanes split K for
// one output at float4 granularity (fully-used 64B lines), reduced with two
// shfl_xor. One block per item (64 blocks), 256 threads, activations ping-pong
// in LDS. Expected floor: streaming 1.5 MB weights per CU ~= 10-13 us.

#define B_ITEMS 64

// Layer: out[M] = act(W[M,K] @ in[K] + b[M]) computed by 256 threads.
// Thread t: output o = (t>>2) + 64*r, K-chunk c = t&3 interleaved per-float4.
template <int M, int K, bool RELU>
__device__ __forceinline__ void layer(const float* __restrict__ W,
                                      const float* __restrict__ bias,
                                      const float* __restrict__ in,   // LDS
                                      float* __restrict__ out,        // LDS
                                      int t) {
    const int c = t & 3;
    const int o0 = t >> 2;
    const float4* __restrict__ A4 = reinterpret_cast<const float4*>(in);
#pragma unroll
    for (int r = 0; r < M / 64; ++r) {
        const int o = o0 + r * 64;
        const float4* __restrict__ W4 =
            reinterpret_cast<const float4*>(W + (size_t)o * K);
        float acc = 0.f;
#pragma unroll
        for (int j = 0; j < K / 16; ++j) {
            float4 w = W4[j * 4 + c];   // 4 lanes -> one full 64B line
            float4 a = A4[j * 4 + c];   // LDS broadcast across groups
            acc = fmaf(w.x, a.x, acc);
            acc = fmaf(w.y, a.y, acc);
            acc = fmaf(w.z, a.z, acc);
            acc = fmaf(w.w, a.w, acc);
        }
        acc += __shfl_xor(acc, 1, 64);
        acc += __shfl_xor(acc, 2, 64);
        if (c == 0) {
            float v = acc + bias[o];
            out[o] = RELU ? fmaxf(v, 0.f) : v;
        }
    }
}

extern "C" __global__ __launch_bounds__(256) void fin_gat_v2(
    const float* __restrict__ x,        // [64,64]
    const int* __restrict__ cidx,       // [64]
    const float* __restrict__ W_in,     // [256,64]
    const float* __restrict__ b_in,     // [256]
    const float* __restrict__ gat_W,    // [3,256,256]
    const float* __restrict__ gat_b,    // [3,256]
    const float* __restrict__ emb,      // [2000,64]
    const float* __restrict__ W_fuse,   // [256,320]
    const float* __restrict__ b_fuse,   // [256]
    const float* __restrict__ W_p1, const float* __restrict__ b_p1,  // [128,256]
    const float* __restrict__ W_p2, const float* __restrict__ b_p2,  // [64,128]
    const float* __restrict__ W_p3, const float* __restrict__ b_p3,  // [1,64]
    const float* __restrict__ W_d1, const float* __restrict__ b_d1,
    const float* __restrict__ W_d2, const float* __restrict__ b_d2,
    const float* __restrict__ W_d3, const float* __restrict__ b_d3,
    float* __restrict__ out)            // [128]
{
    __shared__ float bufA[320];
    __shared__ float bufB[320];

    const int b = blockIdx.x;
    const int t = threadIdx.x;

    // Prefetch x row and company embedding (both 64 floats).
    if (t < 64) {
        const int ci = cidx[b];
        bufA[t] = x[b * 64 + t];
        bufA[256 + t] = emb[(size_t)ci * 64 + t];   // stays until fuse layer
    }
    __syncthreads();

    // h = relu(W_in x + b_in): A[0:64] -> B[0:256]
    layer<256, 64, true>(W_in, b_in, bufA, bufB, t);
    __syncthreads();

    // GAT1: B -> A[0:256]   (A[256:320] = emb, untouched)
    layer<256, 256, true>(gat_W + 0 * 65536, gat_b + 0 * 256, bufB, bufA, t);
    __syncthreads();
    // GAT2: A -> B
    layer<256, 256, true>(gat_W + 1 * 65536, gat_b + 1 * 256, bufA, bufB, t);
    __syncthreads();
    // GAT3: B -> A[0:256]
    layer<256, 256, true>(gat_W + 2 * 65536, gat_b + 2 * 256, bufB, bufA, t);
    __syncthreads();

    // fuse: A[0:320] -> B[0:256]
    layer<256, 320, true>(W_fuse, b_fuse, bufA, bufB, t);
    __syncthreads();

    // p1: B[0:256] -> A[0:128];  d1: B[0:256] -> A[192:320]  (same phase)
    layer<128, 256, true>(W_p1, b_p1, bufB, bufA, t);
    layer<128, 256, true>(W_d1, b_d1, bufB, bufA + 192, t);
    __syncthreads();

    // p2: A[0:128] -> B[0:64];  d2: A[192:320] -> B[64:128]
    layer<64, 128, true>(W_p2, b_p2, bufA, bufB, t);
    layer<64, 128, true>(W_d2, b_d2, bufA + 192, bufB + 64, t);
    __syncthreads();

    // Final dots: wave 0 -> price, wave 1 -> direction.
    if (t < 64) {
        float v = W_p3[t] * bufB[t];
#pragma unroll
        for (int off = 32; off > 0; off >>= 1) v += __shfl_down(v, off, 64);
        if (t == 0) out[b] = v + b_p3[0];
    } else if (t < 128) {
        const int u = t - 64;
        float v = W_d3[u] * bufB[64 + u];
#pragma unroll
        for (int off = 32; off > 0; off >>= 1) v += __shfl_down(v, off, 64);
        if (u == 0) {
            float z = v + b_d3[0];
            out[B_ITEMS + b] = 1.0f / (1.0f + expf(-z));
        }
    }
}

extern "C" void kernel_launch(void* const* d_in, const int* in_sizes, int n_in,
                              void* d_out, int out_size, void* d_ws, size_t ws_size,
                              hipStream_t stream) {
    const float* x      = (const float*)d_in[0];
    const int*   cidx   = (const int*)  d_in[1];
    // d_in[2]=edge_index, d_in[3]=edge_attr -> numerically irrelevant
    const float* W_in   = (const float*)d_in[4];
    const float* b_in   = (const float*)d_in[5];
    const float* gat_W  = (const float*)d_in[6];
    // d_in[7..10] = att params -> irrelevant
    const float* gat_b  = (const float*)d_in[11];
    const float* emb    = (const float*)d_in[12];
    const float* W_fuse = (const float*)d_in[13];
    const float* b_fuse = (const float*)d_in[14];
    const float* W_p1   = (const float*)d_in[15];
    const float* b_p1   = (const float*)d_in[16];
    const float* W_p2   = (const float*)d_in[17];
    const float* b_p2   = (const float*)d_in[18];
    const float* W_p3   = (const float*)d_in[19];
    const float* b_p3   = (const float*)d_in[20];
    const float* W_d1   = (const float*)d_in[21];
    const float* b_d1   = (const float*)d_in[22];
    const float* W_d2   = (const float*)d_in[23];
    const float* b_d2   = (const float*)d_in[24];
    const float* W_d3   = (const float*)d_in[25];
    const float* b_d3   = (const float*)d_in[26];

    fin_gat_v2<<<B_ITEMS, 256, 0, stream>>>(
        x, cidx, W_in, b_in, gat_W, gat_b, emb, W_fuse, b_fuse,
        W_p1, b_p1, W_p2, b_p2, W_p3, b_p3,
        W_d1, b_d1, W_d2, b_d2, W_d3, b_d3,
        (float*)d_out);
}

// Round 3
// 126.030 us; speedup vs baseline: 1.3846x; 1.3846x over previous
//
#include <hip/hip_runtime.h>
#include <math.h>

// EnhancedFinancialGAT — analytical collapse (Round 0 proof: all N=2000 node
// rows identical + per-dst softmax sums to 1 (self-loop guarantees denom>=1)
// => each GAT layer is a dense 256->256 relu; edges/attention irrelevant).
//
// Round 3: latency hiding. R2 showed the kernel is exposed-latency-bound
// (VALUBusy 0.7%, 1 wave/SIMD, weights are cold in HBM every dispatch since
// the harness restores d_in before each launch). Fix: 1024 threads/block
// (16 waves/CU, 4/SIMD) + deeper K-split so each lane's loads are one short
// fully-in-flight burst. G lanes cooperate per output, shfl_xor reduce.

#define B_ITEMS 64

// out[M] = relu(W[M,K] @ in[K] + b). Caller passes t in [0, M*G).
// Lane group c = t%G splits K at float4 granularity (consecutive lanes ->
// consecutive 16B chunks -> full 64B lines).
template <int M, int K, int G>
__device__ __forceinline__ void layerG(const float* __restrict__ W,
                                       const float* __restrict__ bias,
                                       const float* __restrict__ in,   // LDS
                                       float* __restrict__ out,        // LDS
                                       int t) {
    const int c = t & (G - 1);
    const int o = t / G;
    constexpr int NF4 = K / (4 * G);   // float4s per lane
    const float4* __restrict__ W4 =
        reinterpret_cast<const float4*>(W + (size_t)o * K);
    const float4* __restrict__ A4 = reinterpret_cast<const float4*>(in);
    float acc = 0.f;
#pragma unroll
    for (int j = 0; j < NF4; ++j) {
        float4 w = W4[j * G + c];
        float4 a = A4[j * G + c];
        acc = fmaf(w.x, a.x, acc);
        acc = fmaf(w.y, a.y, acc);
        acc = fmaf(w.z, a.z, acc);
        acc = fmaf(w.w, a.w, acc);
    }
#pragma unroll
    for (int s = 1; s < G; s <<= 1) acc += __shfl_xor(acc, s, 64);
    if (c == 0) out[o] = fmaxf(acc + bias[o], 0.f);
}

extern "C" __global__ __launch_bounds__(1024) void fin_gat_v3(
    const float* __restrict__ x,        // [64,64]
    const int* __restrict__ cidx,       // [64]
    const float* __restrict__ W_in,     // [256,64]
    const float* __restrict__ b_in,     // [256]
    const float* __restrict__ gat_W,    // [3,256,256]
    const float* __restrict__ gat_b,    // [3,256]
    const float* __restrict__ emb,      // [2000,64]
    const float* __restrict__ W_fuse,   // [256,320]
    const float* __restrict__ b_fuse,   // [256]
    const float* __restrict__ W_p1, const float* __restrict__ b_p1,  // [128,256]
    const float* __restrict__ W_p2, const float* __restrict__ b_p2,  // [64,128]
    const float* __restrict__ W_p3, const float* __restrict__ b_p3,  // [1,64]
    const float* __restrict__ W_d1, const float* __restrict__ b_d1,
    const float* __restrict__ W_d2, const float* __restrict__ b_d2,
    const float* __restrict__ W_d3, const float* __restrict__ b_d3,
    float* __restrict__ out)            // [128]
{
    __shared__ float bufA[320];
    __shared__ float bufB[320];

    const int b = blockIdx.x;
    const int t = threadIdx.x;

    if (t < 64) {
        const int ci = cidx[b];
        bufA[t] = x[b * 64 + t];
        bufA[256 + t] = emb[(size_t)ci * 64 + t];   // kept for fuse layer
    }
    __syncthreads();

    // h = relu(W_in x): A[0:64] -> B[0:256].  G=4, NF4=4.
    layerG<256, 64, 4>(W_in, b_in, bufA, bufB, t);
    __syncthreads();

    // GAT1..3 (collapsed dense): G=4, NF4=16 each.
    layerG<256, 256, 4>(gat_W + 0 * 65536, gat_b + 0 * 256, bufB, bufA, t);
    __syncthreads();
    layerG<256, 256, 4>(gat_W + 1 * 65536, gat_b + 1 * 256, bufA, bufB, t);
    __syncthreads();
    layerG<256, 256, 4>(gat_W + 2 * 65536, gat_b + 2 * 256, bufB, bufA, t);
    __syncthreads();

    // fuse: A[0:320] -> B[0:256].  G=4, NF4=20.
    layerG<256, 320, 4>(W_fuse, b_fuse, bufA, bufB, t);
    __syncthreads();

    // p1 (lower half-block) / d1 (upper half-block): 128 outs each, G=4.
    if (t < 512) layerG<128, 256, 4>(W_p1, b_p1, bufB, bufA, t);
    else         layerG<128, 256, 4>(W_d1, b_d1, bufB, bufA + 192, t - 512);
    __syncthreads();

    // p2 / d2: 64 outs each, G=8, NF4=4.
    if (t < 512) layerG<64, 128, 8>(W_p2, b_p2, bufA, bufB, t);
    else         layerG<64, 128, 8>(W_d2, b_d2, bufA + 192, bufB + 64, t - 512);
    __syncthreads();

    // Final dots: wave 0 -> price, wave 1 -> direction.
    if (t < 64) {
        float v = W_p3[t] * bufB[t];
#pragma unroll
        for (int off = 32; off > 0; off >>= 1) v += __shfl_down(v, off, 64);
        if (t == 0) out[b] = v + b_p3[0];
    } else if (t < 128) {
        const int u = t - 64;
        float v = W_d3[u] * bufB[64 + u];
#pragma unroll
        for (int off = 32; off > 0; off >>= 1) v += __shfl_down(v, off, 64);
        if (u == 0) {
            float z = v + b_d3[0];
            out[B_ITEMS + b] = 1.0f / (1.0f + expf(-z));
        }
    }
}

extern "C" void kernel_launch(void* const* d_in, const int* in_sizes, int n_in,
                              void* d_out, int out_size, void* d_ws, size_t ws_size,
                              hipStream_t stream) {
    const float* x      = (const float*)d_in[0];
    const int*   cidx   = (const int*)  d_in[1];
    // d_in[2]=edge_index, d_in[3]=edge_attr -> numerically irrelevant
    const float* W_in   = (const float*)d_in[4];
    const float* b_in   = (const float*)d_in[5];
    const float* gat_W  = (const float*)d_in[6];
    // d_in[7..10] = att params -> irrelevant
    const float* gat_b  = (const float*)d_in[11];
    const float* emb    = (const float*)d_in[12];
    const float* W_fuse = (const float*)d_in[13];
    const float* b_fuse = (const float*)d_in[14];
    const float* W_p1   = (const float*)d_in[15];
    const float* b_p1   = (const float*)d_in[16];
    const float* W_p2   = (const float*)d_in[17];
    const float* b_p2   = (const float*)d_in[18];
    const float* W_p3   = (const float*)d_in[19];
    const float* b_p3   = (const float*)d_in[20];
    const float* W_d1   = (const float*)d_in[21];
    const float* b_d1   = (const float*)d_in[22];
    const float* W_d2   = (const float*)d_in[23];
    const float* b_d2   = (const float*)d_in[24];
    const float* W_d3   = (const float*)d_in[25];
    const float* b_d3   = (const float*)d_in[26];

    fin_gat_v3<<<B_ITEMS, 1024, 0, stream>>>(
        x, cidx, W_in, b_in, gat_W, gat_b, emb, W_fuse, b_fuse,
        W_p1, b_p1, W_p2, b_p2, W_p3, b_p3,
        W_d1, b_d1, W_d2, b_d2, W_d3, b_d3,
        (float*)d_out);
}

// Round 4
// 122.384 us; speedup vs baseline: 1.4259x; 1.0298x over previous
//
#include <hip/hip_runtime.h>
#include <math.h>

// EnhancedFinancialGAT — analytical collapse (Round 0 proof: all N=2000 node
// rows identical + per-dst softmax sums to 1 (self-loop guarantees denom>=1)
// => each GAT layer is a dense 256->256 relu; edges/attention irrelevant).
//
// Round 4: XCD-cooperative L2 warming. R3 (16 waves/CU) reached ~34 us but
// every dispatch sees HBM-cold weights (harness restores d_in each launch);
// each layer front-stalls on cold-miss latency. Now the 8 blocks sharing an
// XCD (bid%8==xcd) each sweep a disjoint 1/8 slice of ALL weights via
// global_load_lds (16B touch per 64B line, dead LDS dest) at kernel start,
// pulling the full 1.5 MB into every XCD's L2 in one parallel burst. The
// compiler's vmcnt(0) drain before the first barrier bounds the warm phase;
// all layer reads become L2 hits. Floor: ~1.47 MB/CU at 64 B/cy L1 port
// ~= 10 us.

#define B_ITEMS 64

// Touch one 16B chunk of every 64B line in [p + slice*lps*64, ...), lps lines,
// via async global->LDS (dead scratch). Per-lane gptr, wave-uniform LDS base.
__device__ __forceinline__ void warm_slice(const void* __restrict__ p, int lines,
                                           int slice, void* lds_scratch, int t) {
    const int lps = lines >> 3;   // 8 slices
    const char* base = (const char*)p + (size_t)slice * lps * 64;
    for (int i = t; i < lps; i += 1024) {
        __builtin_amdgcn_global_load_lds(
            (const __attribute__((address_space(1))) void*)(base + (size_t)i * 64),
            (__attribute__((address_space(3))) void*)lds_scratch, 16, 0, 0);
    }
}

__device__ __forceinline__ void warm_full(const void* __restrict__ p, int lines,
                                          void* lds_scratch, int t) {
    const char* base = (const char*)p;
    for (int i = t; i < lines; i += 1024) {
        __builtin_amdgcn_global_load_lds(
            (const __attribute__((address_space(1))) void*)(base + (size_t)i * 64),
            (__attribute__((address_space(3))) void*)lds_scratch, 16, 0, 0);
    }
}

// out[M] = relu(W[M,K] @ in[K] + b). Caller passes t in [0, M*G).
// Lane group c = t%G splits K at float4 granularity.
template <int M, int K, int G>
__device__ __forceinline__ void layerG(const float* __restrict__ W,
                                       const float* __restrict__ bias,
                                       const float* __restrict__ in,   // LDS
                                       float* __restrict__ out,        // LDS
                                       int t) {
    const int c = t & (G - 1);
    const int o = t / G;
    constexpr int NF4 = K / (4 * G);   // float4s per lane
    const float4* __restrict__ W4 =
        reinterpret_cast<const float4*>(W + (size_t)o * K);
    const float4* __restrict__ A4 = reinterpret_cast<const float4*>(in);
    float acc = 0.f;
#pragma unroll
    for (int j = 0; j < NF4; ++j) {
        float4 w = W4[j * G + c];
        float4 a = A4[j * G + c];
        acc = fmaf(w.x, a.x, acc);
        acc = fmaf(w.y, a.y, acc);
        acc = fmaf(w.z, a.z, acc);
        acc = fmaf(w.w, a.w, acc);
    }
#pragma unroll
    for (int s = 1; s < G; s <<= 1) acc += __shfl_xor(acc, s, 64);
    if (c == 0) out[o] = fmaxf(acc + bias[o], 0.f);
}

extern "C" __global__ __launch_bounds__(1024) void fin_gat_v4(
    const float* __restrict__ x,        // [64,64]
    const int* __restrict__ cidx,       // [64]
    const float* __restrict__ W_in,     // [256,64]
    const float* __restrict__ b_in,     // [256]
    const float* __restrict__ gat_W,    // [3,256,256]
    const float* __restrict__ gat_b,    // [3,256]
    const float* __restrict__ emb,      // [2000,64]
    const float* __restrict__ W_fuse,   // [256,320]
    const float* __restrict__ b_fuse,   // [256]
    const float* __restrict__ W_p1, const float* __restrict__ b_p1,  // [128,256]
    const float* __restrict__ W_p2, const float* __restrict__ b_p2,  // [64,128]
    const float* __restrict__ W_p3, const float* __restrict__ b_p3,  // [1,64]
    const float* __restrict__ W_d1, const float* __restrict__ b_d1,
    const float* __restrict__ W_d2, const float* __restrict__ b_d2,
    const float* __restrict__ W_d3, const float* __restrict__ b_d3,
    float* __restrict__ out)            // [128]
{
    __shared__ float bufA[320];
    __shared__ float bufB[320];
    __shared__ float warm_lds[256];     // dead target for warming loads (1 KB)

    const int b = blockIdx.x;
    const int t = threadIdx.x;
    const int slice = b >> 3;           // 8 blocks per XCD cover 8 disjoint slices

    // ---- warm all weight arrays into this XCD's L2 (async, drains at barrier) ----
    warm_slice(gat_W,  12288, slice, warm_lds, t);   // 768 KB
    warm_slice(W_fuse,  5120, slice, warm_lds, t);   // 320 KB
    warm_slice(W_p1,    2048, slice, warm_lds, t);   // 128 KB
    warm_slice(W_d1,    2048, slice, warm_lds, t);   // 128 KB
    warm_slice(W_in,    1024, slice, warm_lds, t);   //  64 KB
    warm_slice(W_p2,     512, slice, warm_lds, t);   //  32 KB
    warm_slice(W_d2,     512, slice, warm_lds, t);   //  32 KB
    warm_full(gat_b, 48, warm_lds, t);               // biases + heads (tiny)
    warm_full(b_in,   4, warm_lds, t);
    warm_full(b_fuse, 4, warm_lds, t);
    warm_full(b_p1,   2, warm_lds, t);
    warm_full(b_d1,   2, warm_lds, t);

    if (t < 64) {
        const int ci = cidx[b];
        bufA[t] = x[b * 64 + t];
        bufA[256 + t] = emb[(size_t)ci * 64 + t];   // kept for fuse layer
    }
    __syncthreads();   // drains warm sweep (vmcnt(0)) + x/emb

    // h = relu(W_in x): A[0:64] -> B[0:256].  G=4.
    layerG<256, 64, 4>(W_in, b_in, bufA, bufB, t);
    __syncthreads();

    // GAT1..3 (collapsed dense): G=4.
    layerG<256, 256, 4>(gat_W + 0 * 65536, gat_b + 0 * 256, bufB, bufA, t);
    __syncthreads();
    layerG<256, 256, 4>(gat_W + 1 * 65536, gat_b + 1 * 256, bufA, bufB, t);
    __syncthreads();
    layerG<256, 256, 4>(gat_W + 2 * 65536, gat_b + 2 * 256, bufB, bufA, t);
    __syncthreads();

    // fuse: A[0:320] -> B[0:256].  G=4.
    layerG<256, 320, 4>(W_fuse, b_fuse, bufA, bufB, t);
    __syncthreads();

    // p1 (lower half-block) / d1 (upper half-block): 128 outs each, G=4.
    if (t < 512) layerG<128, 256, 4>(W_p1, b_p1, bufB, bufA, t);
    else         layerG<128, 256, 4>(W_d1, b_d1, bufB, bufA + 192, t - 512);
    __syncthreads();

    // p2 / d2: 64 outs each, G=8.
    if (t < 512) layerG<64, 128, 8>(W_p2, b_p2, bufA, bufB, t);
    else         layerG<64, 128, 8>(W_d2, b_d2, bufA + 192, bufB + 64, t - 512);
    __syncthreads();

    // Final dots: wave 0 -> price, wave 1 -> direction.
    if (t < 64) {
        float v = W_p3[t] * bufB[t];
#pragma unroll
        for (int off = 32; off > 0; off >>= 1) v += __shfl_down(v, off, 64);
        if (t == 0) out[b] = v + b_p3[0];
    } else if (t < 128) {
        const int u = t - 64;
        float v = W_d3[u] * bufB[64 + u];
#pragma unroll
        for (int off = 32; off > 0; off >>= 1) v += __shfl_down(v, off, 64);
        if (u == 0) {
            float z = v + b_d3[0];
            out[B_ITEMS + b] = 1.0f / (1.0f + expf(-z));
        }
    }
}

extern "C" void kernel_launch(void* const* d_in, const int* in_sizes, int n_in,
                              void* d_out, int out_size, void* d_ws, size_t ws_size,
                              hipStream_t stream) {
    const float* x      = (const float*)d_in[0];
    const int*   cidx   = (const int*)  d_in[1];
    // d_in[2]=edge_index, d_in[3]=edge_attr -> numerically irrelevant
    const float* W_in   = (const float*)d_in[4];
    const float* b_in   = (const float*)d_in[5];
    const float* gat_W  = (const float*)d_in[6];
    // d_in[7..10] = att params -> irrelevant
    const float* gat_b  = (const float*)d_in[11];
    const float* emb    = (const float*)d_in[12];
    const float* W_fuse = (const float*)d_in[13];
    const float* b_fuse = (const float*)d_in[14];
    const float* W_p1   = (const float*)d_in[15];
    const float* b_p1   = (const float*)d_in[16];
    const float* W_p2   = (const float*)d_in[17];
    const float* b_p2   = (const float*)d_in[18];
    const float* W_p3   = (const float*)d_in[19];
    const float* b_p3   = (const float*)d_in[20];
    const float* W_d1   = (const float*)d_in[21];
    const float* b_d1   = (const float*)d_in[22];
    const float* W_d2   = (const float*)d_in[23];
    const float* b_d2   = (const float*)d_in[24];
    const float* W_d3   = (const float*)d_in[25];
    const float* b_d3   = (const float*)d_in[26];

    fin_gat_v4<<<B_ITEMS, 1024, 0, stream>>>(
        x, cidx, W_in, b_in, gat_W, gat_b, emb, W_fuse, b_fuse,
        W_p1, b_p1, W_p2, b_p2, W_p3, b_p3,
        W_d1, b_d1, W_d2, b_d2, W_d3, b_d3,
        (float*)d_out);
}

// Round 5
// 121.804 us; speedup vs baseline: 1.4327x; 1.0048x over previous
//
#include <hip/hip_runtime.h>
#include <math.h>

// EnhancedFinancialGAT — analytical collapse (Round 0 proof: all N=2000 node
// rows identical + per-dst softmax sums to 1 (self-loop guarantees denom>=1)
// => each GAT layer is a dense 256->256 relu; edges/attention irrelevant).
//
// Round 5: fp16 weight compression. R4 showed the kernel is bound by per-CU
// weight streaming volume (1.5 MB fp32 through each CU's L1; warming L2 only
// gained 4 us => latency was already overlapped, bytes are the cost). A
// prepass kernel converts all weight matrices to fp16 in d_ws (must rerun
// every launch; ws is re-poisoned). Main kernel reads half the bytes, issues
// half the vmem instructions, and the freshly-written ws is LLC/L2-warm —
// the R4 warm sweep is now obsolete and removed. Activations/accumulators
// stay fp32; expected absmax ~2e-3 (threshold 1e-2).

#define B_ITEMS 64

typedef _Float16 half_t;
typedef _Float16 half8 __attribute__((ext_vector_type(8)));

// ---- fp16 weight layout inside d_ws (element offsets, all mult. of 8) ----
#define OFF_WIN   0        // W_in   [256x64]   16384
#define OFF_GAT   16384    // gat_W  [3x256x256] 196608
#define OFF_FUSE  212992   // W_fuse [256x320]  81920
#define OFF_P1    294912   // W_p1   [128x256]  32768
#define OFF_D1    327680   // W_d1   [128x256]  32768
#define OFF_P2    360448   // W_p2   [64x128]   8192
#define OFF_D2    368640   // W_d2   [64x128]   8192
#define TOT_W     376832   // total halves (753664 B)

// Prepass: fp32 -> fp16, 8 elements/thread. 46 blocks x 1024 = 47104 threads
// = TOT_W/8 exactly.
extern "C" __global__ __launch_bounds__(1024) void compress_w(
    const float* __restrict__ W_in, const float* __restrict__ gat_W,
    const float* __restrict__ W_fuse, const float* __restrict__ W_p1,
    const float* __restrict__ W_d1, const float* __restrict__ W_p2,
    const float* __restrict__ W_d2, half_t* __restrict__ ws)
{
    const int e = (blockIdx.x * 1024 + threadIdx.x) * 8;
    const float* src;
    int off;
    if      (e < OFF_GAT)  { src = W_in;   off = e; }
    else if (e < OFF_FUSE) { src = gat_W;  off = e - OFF_GAT; }
    else if (e < OFF_P1)   { src = W_fuse; off = e - OFF_FUSE; }
    else if (e < OFF_D1)   { src = W_p1;   off = e - OFF_P1; }
    else if (e < OFF_P2)   { src = W_d1;   off = e - OFF_D1; }
    else if (e < OFF_D2)   { src = W_p2;   off = e - OFF_P2; }
    else                   { src = W_d2;   off = e - OFF_D2; }
    const float4* s4 = reinterpret_cast<const float4*>(src + off);
    float4 a = s4[0], b = s4[1];
    half8 h = { (_Float16)a.x, (_Float16)a.y, (_Float16)a.z, (_Float16)a.w,
                (_Float16)b.x, (_Float16)b.y, (_Float16)b.z, (_Float16)b.w };
    *reinterpret_cast<half8*>(ws + e) = h;
}

// out[M] = relu(Wh[M,K](fp16) @ in[K](fp32 LDS) + b). t in [0, M*G).
// Lane group c = t%G splits K; each chunk = 8 halves (16B load, full-line
// coalescing across 4 consecutive lanes).
template <int M, int K, int G>
__device__ __forceinline__ void layerH(const half_t* __restrict__ Wh,
                                       const float* __restrict__ bias,
                                       const float* __restrict__ in,   // LDS
                                       float* __restrict__ out,        // LDS
                                       int t) {
    const int c = t & (G - 1);
    const int o = t / G;
    constexpr int N8 = K / (8 * G);   // 16B chunks per lane
    const half8* __restrict__ W8 =
        reinterpret_cast<const half8*>(Wh + (size_t)o * K);
    const float4* __restrict__ A4 = reinterpret_cast<const float4*>(in);
    float acc = 0.f;
#pragma unroll
    for (int j = 0; j < N8; ++j) {
        const int idx = j * G + c;
        half8 w = W8[idx];
        float4 a0 = A4[2 * idx];
        float4 a1 = A4[2 * idx + 1];
        acc = fmaf((float)w[0], a0.x, acc);
        acc = fmaf((float)w[1], a0.y, acc);
        acc = fmaf((float)w[2], a0.z, acc);
        acc = fmaf((float)w[3], a0.w, acc);
        acc = fmaf((float)w[4], a1.x, acc);
        acc = fmaf((float)w[5], a1.y, acc);
        acc = fmaf((float)w[6], a1.z, acc);
        acc = fmaf((float)w[7], a1.w, acc);
    }
#pragma unroll
    for (int s = 1; s < G; s <<= 1) acc += __shfl_xor(acc, s, 64);
    if (c == 0) out[o] = fmaxf(acc + bias[o], 0.f);
}

extern "C" __global__ __launch_bounds__(1024) void fin_gat_v5(
    const float* __restrict__ x,        // [64,64]
    const int* __restrict__ cidx,       // [64]
    const half_t* __restrict__ ws,      // fp16 weights (layout above)
    const float* __restrict__ b_in,
    const float* __restrict__ gat_b,    // [3,256]
    const float* __restrict__ emb,      // [2000,64]
    const float* __restrict__ b_fuse,
    const float* __restrict__ b_p1,
    const float* __restrict__ b_p2,
    const float* __restrict__ W_p3, const float* __restrict__ b_p3,  // [1,64]
    const float* __restrict__ b_d1,
    const float* __restrict__ b_d2,
    const float* __restrict__ W_d3, const float* __restrict__ b_d3,
    float* __restrict__ out)            // [128]
{
    __shared__ float bufA[320];
    __shared__ float bufB[320];

    const int b = blockIdx.x;
    const int t = threadIdx.x;

    if (t < 64) {
        const int ci = cidx[b];
        bufA[t] = x[b * 64 + t];
        bufA[256 + t] = emb[(size_t)ci * 64 + t];   // kept for fuse layer
    }
    __syncthreads();

    // h = relu(W_in x): A[0:64] -> B[0:256].  G=4, N8=2.
    layerH<256, 64, 4>(ws + OFF_WIN, b_in, bufA, bufB, t);
    __syncthreads();

    // GAT1..3 (collapsed dense): G=4, N8=8.
    layerH<256, 256, 4>(ws + OFF_GAT + 0 * 65536, gat_b + 0 * 256, bufB, bufA, t);
    __syncthreads();
    layerH<256, 256, 4>(ws + OFF_GAT + 1 * 65536, gat_b + 1 * 256, bufA, bufB, t);
    __syncthreads();
    layerH<256, 256, 4>(ws + OFF_GAT + 2 * 65536, gat_b + 2 * 256, bufB, bufA, t);
    __syncthreads();

    // fuse: A[0:320] -> B[0:256].  G=4, N8=10.
    layerH<256, 320, 4>(ws + OFF_FUSE, b_fuse, bufA, bufB, t);
    __syncthreads();

    // p1 (lower half-block) / d1 (upper half-block): 128 outs each, G=4, N8=8.
    if (t < 512) layerH<128, 256, 4>(ws + OFF_P1, b_p1, bufB, bufA, t);
    else         layerH<128, 256, 4>(ws + OFF_D1, b_d1, bufB, bufA + 192, t - 512);
    __syncthreads();

    // p2 / d2: 64 outs each, G=8, N8=2.
    if (t < 512) layerH<64, 128, 8>(ws + OFF_P2, b_p2, bufA, bufB, t);
    else         layerH<64, 128, 8>(ws + OFF_D2, b_d2, bufA + 192, bufB + 64, t - 512);
    __syncthreads();

    // Final dots (fp32 weights, tiny): wave 0 -> price, wave 1 -> direction.
    if (t < 64) {
        float v = W_p3[t] * bufB[t];
#pragma unroll
        for (int off = 32; off > 0; off >>= 1) v += __shfl_down(v, off, 64);
        if (t == 0) out[b] = v + b_p3[0];
    } else if (t < 128) {
        const int u = t - 64;
        float v = W_d3[u] * bufB[64 + u];
#pragma unroll
        for (int off = 32; off > 0; off >>= 1) v += __shfl_down(v, off, 64);
        if (u == 0) {
            float z = v + b_d3[0];
            out[B_ITEMS + b] = 1.0f / (1.0f + expf(-z));
        }
    }
}

extern "C" void kernel_launch(void* const* d_in, const int* in_sizes, int n_in,
                              void* d_out, int out_size, void* d_ws, size_t ws_size,
                              hipStream_t stream) {
    const float* x      = (const float*)d_in[0];
    const int*   cidx   = (const int*)  d_in[1];
    // d_in[2]=edge_index, d_in[3]=edge_attr -> numerically irrelevant
    const float* W_in   = (const float*)d_in[4];
    const float* b_in   = (const float*)d_in[5];
    const float* gat_W  = (const float*)d_in[6];
    // d_in[7..10] = att params -> irrelevant
    const float* gat_b  = (const float*)d_in[11];
    const float* emb    = (const float*)d_in[12];
    const float* W_fuse = (const float*)d_in[13];
    const float* b_fuse = (const float*)d_in[14];
    const float* W_p1   = (const float*)d_in[15];
    const float* b_p1   = (const float*)d_in[16];
    const float* W_p2   = (const float*)d_in[17];
    const float* b_p2   = (const float*)d_in[18];
    const float* W_p3   = (const float*)d_in[19];
    const float* b_p3   = (const float*)d_in[20];
    const float* W_d1   = (const float*)d_in[21];
    const float* b_d1   = (const float*)d_in[22];
    const float* W_d2   = (const float*)d_in[23];
    const float* b_d2   = (const float*)d_in[24];
    const float* W_d3   = (const float*)d_in[25];
    const float* b_d3   = (const float*)d_in[26];

    half_t* ws = (half_t*)d_ws;   // needs 753664 B of scratch

    // fp32 -> fp16 weight compression (re-runs every launch; ws re-poisoned).
    compress_w<<<46, 1024, 0, stream>>>(W_in, gat_W, W_fuse, W_p1, W_d1,
                                        W_p2, W_d2, ws);

    fin_gat_v5<<<B_ITEMS, 1024, 0, stream>>>(
        x, cidx, ws, b_in, gat_b, emb, b_fuse,
        b_p1, b_p2, W_p3, b_p3, b_d1, b_d2, W_d3, b_d3,
        (float*)d_out);
}

// Round 6
// 116.557 us; speedup vs baseline: 1.4972x; 1.0450x over previous
//
#include <hip/hip_runtime.h>
#include <math.h>

// EnhancedFinancialGAT — analytical collapse (Round 0 proof: all N=2000 node
// rows identical + per-dst softmax sums to 1 (self-loop guarantees denom>=1)
// => each GAT layer is a dense 256->256 relu; edges/attention irrelevant).
//
// Round 6: cross-layer software pipelining. R4 (L2 warm) and R5 (fp16 bytes)
// were both ~neutral => the main kernel is latency-serialized at layer
// boundaries, not byte-bound. Weight loads depend on nothing, so each layer's
// weight fragment is prefetched into REGISTERS while the previous layer
// computes (one layer ahead; max live frags 72 VGPRs, fits the 128-VGPR cap
// of 1024-thread blocks). All biases staged to LDS in the initial burst;
// final dot weights preloaded to registers. Per-layer critical path becomes
// LDS read + 64 fma + shfl reduce + barrier.

#define B_ITEMS 64

typedef _Float16 half_t;
typedef _Float16 half8 __attribute__((ext_vector_type(8)));

// ---- fp16 weight layout inside d_ws (element offsets, all mult. of 8) ----
#define OFF_WIN   0        // W_in   [256x64]   16384
#define OFF_GAT   16384    // gat_W  [3x256x256] 196608
#define OFF_FUSE  212992   // W_fuse [256x320]  81920
#define OFF_P1    294912   // W_p1   [128x256]  32768
#define OFF_D1    327680   // W_d1   [128x256]  32768
#define OFF_P2    360448   // W_p2   [64x128]   8192
#define OFF_D2    368640   // W_d2   [64x128]   8192
#define TOT_W     376832   // total halves (753664 B)

// ---- bias layout in LDS (float offsets) ----
#define BIN   0      // 256
#define BGAT  256    // 768 (3*256)
#define BFUSE 1024   // 256
#define BP1   1280   // 128
#define BD1   1408   // 128
#define BP2   1536   // 64
#define BD2   1600   // 64
#define NBIAS 1664

// Prepass: fp32 -> fp16, 8 elements/thread. 46 x 1024 threads = TOT_W/8.
extern "C" __global__ __launch_bounds__(1024) void compress_w(
    const float* __restrict__ W_in, const float* __restrict__ gat_W,
    const float* __restrict__ W_fuse, const float* __restrict__ W_p1,
    const float* __restrict__ W_d1, const float* __restrict__ W_p2,
    const float* __restrict__ W_d2, half_t* __restrict__ ws)
{
    const int e = (blockIdx.x * 1024 + threadIdx.x) * 8;
    const float* src;
    int off;
    if      (e < OFF_GAT)  { src = W_in;   off = e; }
    else if (e < OFF_FUSE) { src = gat_W;  off = e - OFF_GAT; }
    else if (e < OFF_P1)   { src = W_fuse; off = e - OFF_FUSE; }
    else if (e < OFF_D1)   { src = W_p1;   off = e - OFF_P1; }
    else if (e < OFF_P2)   { src = W_d1;   off = e - OFF_D1; }
    else if (e < OFF_D2)   { src = W_p2;   off = e - OFF_P2; }
    else                   { src = W_d2;   off = e - OFF_D2; }
    const float4* s4 = reinterpret_cast<const float4*>(src + off);
    float4 a = s4[0], b = s4[1];
    half8 h = { (_Float16)a.x, (_Float16)a.y, (_Float16)a.z, (_Float16)a.w,
                (_Float16)b.x, (_Float16)b.y, (_Float16)b.z, (_Float16)b.w };
    *reinterpret_cast<half8*>(ws + e) = h;
}

// Weight fragment for one layer: this lane's K-slice of its output row.
template <int K, int G>
struct WFrag { half8 w[K / (8 * G)]; };

template <int K, int G>
__device__ __forceinline__ void load_frag(WFrag<K, G>& f,
                                          const half_t* __restrict__ Wh, int t) {
    const int c = t & (G - 1);
    const int o = t / G;
    const half8* __restrict__ W8 =
        reinterpret_cast<const half8*>(Wh + (size_t)o * K);
#pragma unroll
    for (int j = 0; j < K / (8 * G); ++j) f.w[j] = W8[j * G + c];
}

// out[M] = relu(frag @ in + b), frag already in registers. t in [0, M*G).
template <int M, int K, int G>
__device__ __forceinline__ void compute_frag(const WFrag<K, G>& f,
                                             const float* __restrict__ bias,  // LDS
                                             const float* __restrict__ in,    // LDS
                                             float* __restrict__ out,         // LDS
                                             int t) {
    const int c = t & (G - 1);
    const int o = t / G;
    const float4* __restrict__ A4 = reinterpret_cast<const float4*>(in);
    float acc = 0.f;
#pragma unroll
    for (int j = 0; j < K / (8 * G); ++j) {
        const int idx = j * G + c;
        float4 a0 = A4[2 * idx];
        float4 a1 = A4[2 * idx + 1];
        half8 w = f.w[j];
        acc = fmaf((float)w[0], a0.x, acc);
        acc = fmaf((float)w[1], a0.y, acc);
        acc = fmaf((float)w[2], a0.z, acc);
        acc = fmaf((float)w[3], a0.w, acc);
        acc = fmaf((float)w[4], a1.x, acc);
        acc = fmaf((float)w[5], a1.y, acc);
        acc = fmaf((float)w[6], a1.z, acc);
        acc = fmaf((float)w[7], a1.w, acc);
    }
#pragma unroll
    for (int s = 1; s < G; s <<= 1) acc += __shfl_xor(acc, s, 64);
    if (c == 0) out[o] = fmaxf(acc + bias[o], 0.f);
}

extern "C" __global__ __launch_bounds__(1024) void fin_gat_v6(
    const float* __restrict__ x,        // [64,64]
    const int* __restrict__ cidx,       // [64]
    const half_t* __restrict__ ws,      // fp16 weights (layout above)
    const float* __restrict__ b_in,
    const float* __restrict__ gat_b,    // [3,256]
    const float* __restrict__ emb,      // [2000,64]
    const float* __restrict__ b_fuse,
    const float* __restrict__ b_p1,
    const float* __restrict__ b_p2,
    const float* __restrict__ W_p3, const float* __restrict__ b_p3,
    const float* __restrict__ b_d1,
    const float* __restrict__ b_d2,
    const float* __restrict__ W_d3, const float* __restrict__ b_d3,
    float* __restrict__ out)            // [128]
{
    __shared__ float bufA[320];
    __shared__ float bufB[320];
    __shared__ float bias_lds[NBIAS];

    const int b = blockIdx.x;
    const int t = threadIdx.x;

    // ---- initial burst: L0 weights, x/emb, all biases, head dot weights ----
    WFrag<64, 4> f_in;
    load_frag(f_in, ws + OFF_WIN, t);

    if (t < 64) {
        const int ci = cidx[b];
        bufA[t] = x[b * 64 + t];
        bufA[256 + t] = emb[(size_t)ci * 64 + t];   // kept for fuse layer
    }
    float wdot = 0.f, bdot = 0.f;
    if (t < 64)            wdot = W_p3[t];
    else if (t < 128)      wdot = W_d3[t - 64];
    if (t == 0)            bdot = b_p3[0];
    else if (t == 64)      bdot = b_d3[0];

#pragma unroll
    for (int i = t; i < NBIAS; i += 1024) {
        float v;
        if      (i < 256)  v = b_in[i];
        else if (i < 1024) v = gat_b[i - 256];
        else if (i < 1280) v = b_fuse[i - 1024];
        else if (i < 1408) v = b_p1[i - 1280];
        else if (i < 1536) v = b_d1[i - 1408];
        else if (i < 1600) v = b_p2[i - 1536];
        else               v = b_d2[i - 1600];
        bias_lds[i] = v;
    }
    __syncthreads();

    // ---- L0: h = relu(W_in x): A[0:64] -> B[0:256] ----
    WFrag<256, 4> fg0;
    load_frag(fg0, ws + OFF_GAT + 0 * 65536, t);            // prefetch L1
    compute_frag<256, 64, 4>(f_in, bias_lds + BIN, bufA, bufB, t);
    __syncthreads();

    // ---- L1 (GAT1): B -> A[0:256]  (emb intact in A[256:320]) ----
    WFrag<256, 4> fg1;
    load_frag(fg1, ws + OFF_GAT + 1 * 65536, t);            // prefetch L2
    compute_frag<256, 256, 4>(fg0, bias_lds + BGAT, bufB, bufA, t);
    __syncthreads();

    // ---- L2 (GAT2): A -> B ----
    WFrag<256, 4> fg2;
    load_frag(fg2, ws + OFF_GAT + 2 * 65536, t);            // prefetch L3
    compute_frag<256, 256, 4>(fg1, bias_lds + BGAT + 256, bufA, bufB, t);
    __syncthreads();

    // ---- L3 (GAT3): B -> A[0:256] ----
    WFrag<320, 4> f_fu;
    load_frag(f_fu, ws + OFF_FUSE, t);                      // prefetch fuse
    compute_frag<256, 256, 4>(fg2, bias_lds + BGAT + 512, bufB, bufA, t);
    __syncthreads();

    // ---- L4 (fuse): A[0:320] -> B[0:256] ----
    WFrag<256, 4> f_h1;
    load_frag(f_h1, (t < 512) ? ws + OFF_P1 : ws + OFF_D1, t & 511);  // prefetch heads-1
    compute_frag<256, 320, 4>(f_fu, bias_lds + BFUSE, bufA, bufB, t);
    __syncthreads();

    // ---- L5: p1 (lower half-block) / d1 (upper half-block) ----
    WFrag<128, 8> f_h2;
    load_frag(f_h2, (t < 512) ? ws + OFF_P2 : ws + OFF_D2, t & 511);  // prefetch heads-2
    if (t < 512) compute_frag<128, 256, 4>(f_h1, bias_lds + BP1, bufB, bufA, t);
    else         compute_frag<128, 256, 4>(f_h1, bias_lds + BD1, bufB, bufA + 192, t - 512);
    __syncthreads();

    // ---- L6: p2 / d2 ----
    if (t < 512) compute_frag<64, 128, 8>(f_h2, bias_lds + BP2, bufA, bufB, t);
    else         compute_frag<64, 128, 8>(f_h2, bias_lds + BD2, bufA + 192, bufB + 64, t - 512);
    __syncthreads();

    // ---- final dots (weights preloaded): wave 0 -> price, wave 1 -> dir ----
    if (t < 64) {
        float v = wdot * bufB[t];
#pragma unroll
        for (int off = 32; off > 0; off >>= 1) v += __shfl_down(v, off, 64);
        if (t == 0) out[b] = v + bdot;
    } else if (t < 128) {
        const int u = t - 64;
        float v = wdot * bufB[64 + u];
#pragma unroll
        for (int off = 32; off > 0; off >>= 1) v += __shfl_down(v, off, 64);
        if (u == 0) {
            float z = v + bdot;
            out[B_ITEMS + b] = 1.0f / (1.0f + expf(-z));
        }
    }
}

extern "C" void kernel_launch(void* const* d_in, const int* in_sizes, int n_in,
                              void* d_out, int out_size, void* d_ws, size_t ws_size,
                              hipStream_t stream) {
    const float* x      = (const float*)d_in[0];
    const int*   cidx   = (const int*)  d_in[1];
    // d_in[2]=edge_index, d_in[3]=edge_attr -> numerically irrelevant
    const float* W_in   = (const float*)d_in[4];
    const float* b_in   = (const float*)d_in[5];
    const float* gat_W  = (const float*)d_in[6];
    // d_in[7..10] = att params -> irrelevant
    const float* gat_b  = (const float*)d_in[11];
    const float* emb    = (const float*)d_in[12];
    const float* W_fuse = (const float*)d_in[13];
    const float* b_fuse = (const float*)d_in[14];
    const float* W_p1   = (const float*)d_in[15];
    const float* b_p1   = (const float*)d_in[16];
    const float* W_p2   = (const float*)d_in[17];
    const float* b_p2   = (const float*)d_in[18];
    const float* W_p3   = (const float*)d_in[19];
    const float* b_p3   = (const float*)d_in[20];
    const float* W_d1   = (const float*)d_in[21];
    const float* b_d1   = (const float*)d_in[22];
    const float* W_d2   = (const float*)d_in[23];
    const float* b_d2   = (const float*)d_in[24];
    const float* W_d3   = (const float*)d_in[25];
    const float* b_d3   = (const float*)d_in[26];

    half_t* ws = (half_t*)d_ws;   // needs 753664 B of scratch

    compress_w<<<46, 1024, 0, stream>>>(W_in, gat_W, W_fuse, W_p1, W_d1,
                                        W_p2, W_d2, ws);

    fin_gat_v6<<<B_ITEMS, 1024, 0, stream>>>(
        x, cidx, ws, b_in, gat_b, emb, b_fuse,
        b_p1, b_p2, W_p3, b_p3, b_d1, b_d2, W_d3, b_d3,
        (float*)d_out);
}